// Round 7
// baseline (235.803 us; speedup 1.0000x reference)
//
#include <hip/hip_runtime.h>

// out[b,t,:] = relu((mean_t(x_b) @ Wk + bk) @ Wl + bl)   [double-softmax ≈ uniform, validated r3-r5]
// Single kernel + memset node. One custom device-scope barrier (grid.sync measured ~90µs -> avoid).
// Phase A: colsum(x) -> atomic msum  ||  Wkl=Wk@Wl tiles  ||  bkl=bk@Wl+bl   (independent work)
// barrier (atomic cnt, s_sleep spin)
// Phase B: each block: m -> outc slice (32 cols) via m@Wkl+bkl
// Phase C: each block writes its 128-row x 32-col output stripe.

#define NBLK 1024

__global__ __launch_bounds__(256) void k_fused(const float* __restrict__ x,
    const float* __restrict__ Wk, const float* __restrict__ bk,
    const float* __restrict__ Wl, const float* __restrict__ bl,
    unsigned int* __restrict__ cnt, float* __restrict__ msum,
    float* __restrict__ Wkl, float* __restrict__ bkl,
    float* __restrict__ out) {
  int bid = blockIdx.x, tid = threadIdx.x;
  __shared__ float4 lred[3][64];
  __shared__ float red[256];
  __shared__ float m_lds[256];
  __shared__ float outc[32];

  int b = bid >> 8;

  // ---- Phase A1: column-sum of this block's 16 rows -> atomicAdd msum[b][:]
  {
    const float4* xr = (const float4*)(x + (size_t)bid * 16 * 256);
    int d4 = tid & 63, rs = tid >> 6;
    float4 acc = {0.f, 0.f, 0.f, 0.f};
#pragma unroll
    for (int i = 0; i < 4; ++i) {
      float4 v = xr[(size_t)(rs * 4 + i) * 64 + d4];
      acc.x += v.x; acc.y += v.y; acc.z += v.z; acc.w += v.w;
    }
    if (rs) lred[rs - 1][d4] = acc;
    __syncthreads();
    if (rs == 0) {
      float4 a1 = lred[0][d4], a2 = lred[1][d4], a3 = lred[2][d4];
      acc.x += a1.x + a2.x + a3.x;
      acc.y += a1.y + a2.y + a3.y;
      acc.z += a1.z + a2.z + a3.z;
      acc.w += a1.w + a2.w + a3.w;
      atomicAdd(&msum[b * 256 + d4 * 4 + 0], acc.x);
      atomicAdd(&msum[b * 256 + d4 * 4 + 1], acc.y);
      atomicAdd(&msum[b * 256 + d4 * 4 + 2], acc.z);
      atomicAdd(&msum[b * 256 + d4 * 4 + 3], acc.w);
    }
  }

  // ---- Phase A2: Wkl 8x8 tile (x-independent; overlaps colsum across blocks)
  {
    int i0 = (bid >> 5) * 8, j0 = (bid & 31) * 8;
    int oi = tid & 63, ks = tid >> 6;                  // 64 outputs x 4 K-splits
    int i = i0 + (oi >> 3), j = j0 + (oi & 7);
    const float* wkr = Wk + i * 256 + ks * 64;
    const float* wlc = Wl + (ks * 64) * 256 + j;
    float s0 = 0.f, s1 = 0.f, s2 = 0.f, s3 = 0.f;
    for (int k = 0; k < 64; k += 4) {
      s0 += wkr[k + 0] * wlc[(k + 0) * 256];
      s1 += wkr[k + 1] * wlc[(k + 1) * 256];
      s2 += wkr[k + 2] * wlc[(k + 2) * 256];
      s3 += wkr[k + 3] * wlc[(k + 3) * 256];
    }
    red[tid] = s0 + s1 + s2 + s3;
    __syncthreads();
    if (tid < 64) {
      int ii = i0 + (tid >> 3), jj = j0 + (tid & 7);
      Wkl[ii * 256 + jj] = red[tid] + red[tid + 64] + red[tid + 128] + red[tid + 192];
    }
  }
  // ---- Phase A3: bkl (blocks 0..31, 8 cols each)
  if (bid < 32) {
    int c = tid & 7, ks = tid >> 3;                    // 8 cols x 32 K-splits
    int j = bid * 8 + c;
    float s = 0.f;
#pragma unroll
    for (int i2 = ks * 8; i2 < ks * 8 + 8; ++i2) s += bk[i2] * Wl[i2 * 256 + j];
    __syncthreads();                                    // red reuse fence
    red[tid] = s;
    __syncthreads();
    if (tid < 8) {
      float t = 0.f;
#pragma unroll
      for (int g = 0; g < 32; ++g) t += red[g * 8 + tid];
      bkl[bid * 8 + tid] = t + bl[bid * 8 + tid];
    }
  }

  // ---- custom barrier: release-add, relaxed spin, acquire on exit
  __threadfence();
  __syncthreads();
  if (tid == 0) {
    __hip_atomic_fetch_add(cnt, 1u, __ATOMIC_RELEASE, __HIP_MEMORY_SCOPE_AGENT);
    int spins = 0;
    while (__hip_atomic_load(cnt, __ATOMIC_RELAXED, __HIP_MEMORY_SCOPE_AGENT) < NBLK) {
      __builtin_amdgcn_s_sleep(8);
      if (++spins > 4000000) break;                     // safety valve: fail, don't hang
    }
    (void)__hip_atomic_load(cnt, __ATOMIC_ACQUIRE, __HIP_MEMORY_SCOPE_AGENT);
  }
  __syncthreads();

  // ---- Phase B: outc[b][cg*32 .. +32] = relu(m @ Wkl + bkl) for this block's slice
  int cg = (bid >> 5) & 7, rg = bid & 31;
  {
    float mv = __hip_atomic_load(&msum[b * 256 + tid], __ATOMIC_RELAXED, __HIP_MEMORY_SCOPE_AGENT);
    m_lds[tid] = mv * (1.0f / 4096.0f);
    __syncthreads();
    int c = tid & 31, ks = tid >> 5;                   // 32 cols x 8 K-splits
    const float* wcol = Wkl + cg * 32 + c;
    float a0 = 0.f, a1 = 0.f, a2 = 0.f, a3 = 0.f;
    int p0 = ks * 32;
    for (int p = p0; p < p0 + 32; p += 4) {
      a0 += m_lds[p + 0] * wcol[(p + 0) * 256];
      a1 += m_lds[p + 1] * wcol[(p + 1) * 256];
      a2 += m_lds[p + 2] * wcol[(p + 2) * 256];
      a3 += m_lds[p + 3] * wcol[(p + 3) * 256];
    }
    red[tid] = a0 + a1 + a2 + a3;
    __syncthreads();
    if (tid < 32) {
      float v = bkl[cg * 32 + tid];
#pragma unroll
      for (int g = 0; g < 8; ++g) v += red[g * 32 + tid];
      outc[tid] = v > 0.f ? v : 0.f;
    }
    __syncthreads();
  }

  // ---- Phase C: write 128 rows x 32 cols
  {
    int f4c = tid & 7, r0 = tid >> 3;                  // 8 float4-cols x 32 rows/pass
    float4 c4 = {outc[f4c * 4], outc[f4c * 4 + 1], outc[f4c * 4 + 2], outc[f4c * 4 + 3]};
    size_t base = ((size_t)b * 4096 + (size_t)rg * 128) * 256 + cg * 32;
#pragma unroll
    for (int pass = 0; pass < 4; ++pass) {
      int row = pass * 32 + r0;
      *(float4*)(out + base + (size_t)row * 256 + f4c * 4) = c4;
    }
  }
}

extern "C" void kernel_launch(void* const* d_in, const int* in_sizes, int n_in,
                              void* d_out, int out_size, void* d_ws, size_t ws_size,
                              hipStream_t stream) {
  const float* x  = (const float*)d_in[0];
  const float* Wk = (const float*)d_in[3];
  const float* bk = (const float*)d_in[4];
  const float* Wl = (const float*)d_in[7];
  const float* bl = (const float*)d_in[8];

  char* ws = (char*)d_ws;
  unsigned int* cnt = (unsigned int*)ws;               // 4B (pad to 256)
  float* msum = (float*)(ws + 256);                    // 4KB
  float* Wkl  = (float*)(ws + 8192);                   // 256KB
  float* bkl  = (float*)(ws + 8192 + 262144);          // 1KB
  float* out  = (float*)d_out;

  // reset barrier counter + msum accumulators (graph-capturable async memset)
  hipMemsetAsync(ws, 0, 4352, stream);

  void* args[] = {&x, &Wk, &bk, &Wl, &bl, &cnt, &msum, &Wkl, &bkl, &out};
  hipLaunchCooperativeKernel((void*)k_fused, dim3(NBLK), dim3(256), args, 0, stream);
}

// Round 8
// 75.612 us; speedup vs baseline: 3.1186x; 3.1186x over previous
//
#include <hip/hip_runtime.h>

// out[b,t,:] = relu((mean_t(x_b) @ Wk + bk) @ Wl + bl)   [double-softmax ≈ uniform; validated r3-r5]
//
// Single dispatch, NO fences (r6/r7 showed grid.sync / threadfence cost ~90-210us:
// per-block agent-scope release/acquire emits per-XCD L2 writeback/invalidate).
// All cross-block data flows through relaxed agent-scope atomics (IF-coherent, no cache flush):
//   colsum -> atomicAdd msum[b][:]
//   per-batch counter RMW; the block whose add returns 255 is last -> does the combine
//   combine -> relaxed atomic stores to outc[b][:], then flag[b]=1
//   every block polls flag[b] (s_sleep), reads outc, writes its 16-row stripe.
// Ordering uses only s_waitcnt vmcnt(0) (drain own atomics), never cache maintenance.

__global__ __launch_bounds__(256) void k_all(const float* __restrict__ x,
    const float* __restrict__ Wk, const float* __restrict__ bk,
    const float* __restrict__ Wl, const float* __restrict__ bl,
    unsigned int* __restrict__ cnt, unsigned int* __restrict__ flag,
    float* __restrict__ msum, float* __restrict__ outc,
    float* __restrict__ out) {
  int bid = blockIdx.x, tid = threadIdx.x;
  int b = bid >> 8;                       // batch (256 blocks per batch)
  int d4 = tid & 63, rs = tid >> 6;
  __shared__ float4 lred[3][64];
  __shared__ float sA[256], sB[256];
  __shared__ int amLast;

  // ---- Phase A: column-sum of this block's 16 rows -> atomicAdd msum[b][:]
  {
    const float4* xr = (const float4*)(x + (size_t)bid * 16 * 256);
    float4 acc = {0.f, 0.f, 0.f, 0.f};
#pragma unroll
    for (int i = 0; i < 4; ++i) {
      float4 v = xr[(size_t)(rs * 4 + i) * 64 + d4];
      acc.x += v.x; acc.y += v.y; acc.z += v.z; acc.w += v.w;
    }
    if (rs) lred[rs - 1][d4] = acc;
    __syncthreads();
    if (rs == 0) {
      float4 a1 = lred[0][d4], a2 = lred[1][d4], a3 = lred[2][d4];
      acc.x += a1.x + a2.x + a3.x;
      acc.y += a1.y + a2.y + a3.y;
      acc.z += a1.z + a2.z + a3.z;
      acc.w += a1.w + a2.w + a3.w;
      float* mb = msum + b * 256 + d4 * 4;
      __hip_atomic_fetch_add(mb + 0, acc.x, __ATOMIC_RELAXED, __HIP_MEMORY_SCOPE_AGENT);
      __hip_atomic_fetch_add(mb + 1, acc.y, __ATOMIC_RELAXED, __HIP_MEMORY_SCOPE_AGENT);
      __hip_atomic_fetch_add(mb + 2, acc.z, __ATOMIC_RELAXED, __HIP_MEMORY_SCOPE_AGENT);
      __hip_atomic_fetch_add(mb + 3, acc.w, __ATOMIC_RELAXED, __HIP_MEMORY_SCOPE_AGENT);
    }
    asm volatile("s_waitcnt vmcnt(0)" ::: "memory");  // own msum adds complete (no cache op)
    __syncthreads();
  }

  // ---- arrival count; last block of this batch does the combine
  if (tid == 0) {
    unsigned int old = __hip_atomic_fetch_add(&cnt[b], 1u, __ATOMIC_RELAXED, __HIP_MEMORY_SCOPE_AGENT);
    amLast = (old == 255u);
  }
  __syncthreads();

  if (amLast) {
    // combine: m = msum/4096; t1 = m@Wk+bk; outc = relu(t1@Wl+bl)
    float mv = __hip_atomic_load(&msum[b * 256 + tid], __ATOMIC_RELAXED, __HIP_MEMORY_SCOPE_AGENT);
    sA[tid] = mv * (1.0f / 4096.0f);
    __syncthreads();
    {
      const float* wc = Wk + tid;
      float a0 = 0.f, a1 = 0.f, a2 = 0.f, a3 = 0.f;
      for (int i = 0; i < 256; i += 4) {
        a0 += sA[i + 0] * wc[(i + 0) * 256];
        a1 += sA[i + 1] * wc[(i + 1) * 256];
        a2 += sA[i + 2] * wc[(i + 2) * 256];
        a3 += sA[i + 3] * wc[(i + 3) * 256];
      }
      sB[tid] = a0 + a1 + a2 + a3 + bk[tid];
    }
    __syncthreads();
    {
      const float* wc = Wl + tid;
      float c0 = 0.f, c1 = 0.f, c2 = 0.f, c3 = 0.f;
      for (int i = 0; i < 256; i += 4) {
        c0 += sB[i + 0] * wc[(i + 0) * 256];
        c1 += sB[i + 1] * wc[(i + 1) * 256];
        c2 += sB[i + 2] * wc[(i + 2) * 256];
        c3 += sB[i + 3] * wc[(i + 3) * 256];
      }
      float v = c0 + c1 + c2 + c3 + bl[tid];
      v = v > 0.f ? v : 0.f;
      __hip_atomic_store(&outc[b * 256 + tid], v, __ATOMIC_RELAXED, __HIP_MEMORY_SCOPE_AGENT);
    }
    asm volatile("s_waitcnt vmcnt(0)" ::: "memory");  // outc stores complete
    __syncthreads();
    if (tid == 0)
      __hip_atomic_store(&flag[b], 1u, __ATOMIC_RELAXED, __HIP_MEMORY_SCOPE_AGENT);
  }

  // ---- Phase C: wait for this batch's outc, then write 16-row output stripe
  if (tid == 0) {
    long spins = 0;
    while (__hip_atomic_load(&flag[b], __ATOMIC_RELAXED, __HIP_MEMORY_SCOPE_AGENT) == 0u) {
      __builtin_amdgcn_s_sleep(16);
      if (++spins > 2000000L) break;   // safety valve: visible failure, never a hang
    }
  }
  __syncthreads();
  sA[tid] = __hip_atomic_load(&outc[b * 256 + tid], __ATOMIC_RELAXED, __HIP_MEMORY_SCOPE_AGENT);
  __syncthreads();
  {
    float4 c4 = {sA[d4 * 4], sA[d4 * 4 + 1], sA[d4 * 4 + 2], sA[d4 * 4 + 3]};
    float4* o = (float4*)(out + (size_t)bid * 16 * 256);
#pragma unroll
    for (int i = 0; i < 4; ++i) o[(size_t)(rs * 4 + i) * 64 + d4] = c4;
  }
}

extern "C" void kernel_launch(void* const* d_in, const int* in_sizes, int n_in,
                              void* d_out, int out_size, void* d_ws, size_t ws_size,
                              hipStream_t stream) {
  const float* x  = (const float*)d_in[0];
  const float* Wk = (const float*)d_in[3];
  const float* bk = (const float*)d_in[4];
  const float* Wl = (const float*)d_in[7];
  const float* bl = (const float*)d_in[8];

  char* ws = (char*)d_ws;
  unsigned int* cnt  = (unsigned int*)ws;          // 16 B
  unsigned int* flag = (unsigned int*)(ws + 64);   // 16 B
  float* msum = (float*)(ws + 256);                // 4 KB
  float* outc = (float*)(ws + 8192);               // 4 KB (no reset needed)
  float* out  = (float*)d_out;

  hipMemsetAsync(ws, 0, 4352, stream);             // zero cnt, flag, msum each call

  k_all<<<dim3(1024), dim3(256), 0, stream>>>(x, Wk, bk, Wl, bl, cnt, flag, msum, outc, out);
}

// Round 9
// 20.478 us; speedup vs baseline: 11.5148x; 3.6923x over previous
//
#include <hip/hip_runtime.h>

// out[b,t,:] = relu(mean_t(x_b) @ Wkl + bkl),  Wkl = Wk@Wl,  bkl = bk@Wl + bl
// (double-softmax attention is uniform to O(1e-8); validated r3-r5.)
//
// Two dispatches, ZERO device-scope sync (r6/r7/r8 measured: any in-kernel
// cross-block sync >= 45us over a kernel boundary on gfx950's 8-XCD fabric).
// Stage 2 trades a tiny redundant reduce (64KB/block from L2) for all syncs.

#define CSB 256      // colsum blocks (64 rows each)
#define WKB 1024     // Wkl tile blocks (8x8 tile each)
#define BKB 32       // bkl blocks (8 cols each)

__global__ __launch_bounds__(256) void k_stage1(const float* __restrict__ x,
    const float* __restrict__ Wk, const float* __restrict__ bk,
    const float* __restrict__ Wl, const float* __restrict__ bl,
    float* __restrict__ partial, float* __restrict__ Wkl,
    float* __restrict__ bkl) {
  int bid = blockIdx.x, tid = threadIdx.x;
  __shared__ float4 lred[3][64];
  __shared__ float red[256];

  if (bid < CSB) {
    // ---- column-sum of 64 rows of x -> partial[bid][0..255]
    const float4* xr = (const float4*)(x + (size_t)bid * 64 * 256);
    int d4 = tid & 63, rs = tid >> 6;
    float4 acc = {0.f, 0.f, 0.f, 0.f};
#pragma unroll
    for (int i = 0; i < 16; ++i) {
      float4 v = xr[(size_t)(rs * 16 + i) * 64 + d4];
      acc.x += v.x; acc.y += v.y; acc.z += v.z; acc.w += v.w;
    }
    if (rs) lred[rs - 1][d4] = acc;
    __syncthreads();
    if (rs == 0) {
      float4 a1 = lred[0][d4], a2 = lred[1][d4], a3 = lred[2][d4];
      acc.x += a1.x + a2.x + a3.x;
      acc.y += a1.y + a2.y + a3.y;
      acc.z += a1.z + a2.z + a3.z;
      acc.w += a1.w + a2.w + a3.w;
      ((float4*)(partial + (size_t)bid * 256))[d4] = acc;
    }
  } else if (bid < CSB + WKB) {
    // ---- Wkl = Wk@Wl, one 8x8 tile per block (64 outputs x 4 K-splits)
    int t = bid - CSB;
    int i0 = (t >> 5) * 8, j0 = (t & 31) * 8;
    int oi = tid & 63, ks = tid >> 6;
    int i = i0 + (oi >> 3), j = j0 + (oi & 7);
    const float* wkr = Wk + i * 256 + ks * 64;
    const float* wlc = Wl + (ks * 64) * 256 + j;
    float s0 = 0.f, s1 = 0.f, s2 = 0.f, s3 = 0.f;
    for (int k = 0; k < 64; k += 4) {
      s0 += wkr[k + 0] * wlc[(k + 0) * 256];
      s1 += wkr[k + 1] * wlc[(k + 1) * 256];
      s2 += wkr[k + 2] * wlc[(k + 2) * 256];
      s3 += wkr[k + 3] * wlc[(k + 3) * 256];
    }
    red[tid] = s0 + s1 + s2 + s3;
    __syncthreads();
    if (tid < 64) {
      int ii = i0 + (tid >> 3), jj = j0 + (tid & 7);
      Wkl[ii * 256 + jj] = red[tid] + red[tid + 64] + red[tid + 128] + red[tid + 192];
    }
  } else {
    // ---- bkl = bk@Wl + bl, 8 cols per block (8 cols x 32 K-splits)
    int t = bid - CSB - WKB;
    int c = tid & 7, ks = tid >> 3;
    int j = t * 8 + c;
    float s = 0.f;
#pragma unroll
    for (int i2 = ks * 8; i2 < ks * 8 + 8; ++i2) s += bk[i2] * Wl[i2 * 256 + j];
    red[tid] = s;
    __syncthreads();
    if (tid < 8) {
      float v = 0.f;
#pragma unroll
      for (int g = 0; g < 32; ++g) v += red[g * 8 + tid];
      bkl[t * 8 + tid] = v + bl[t * 8 + tid];
    }
  }
}

__global__ __launch_bounds__(256) void k_stage2(const float* __restrict__ partial,
    const float* __restrict__ Wkl, const float* __restrict__ bkl,
    float* __restrict__ out) {
  // bid -> (b, cg, rg): batch, 32-col group (8), 128-row group (32)
  int bid = blockIdx.x, tid = threadIdx.x;
  int b = bid >> 8, cg = (bid >> 5) & 7, rg = bid & 31;
  __shared__ float m[256];
  __shared__ float red[256];
  __shared__ float oc[32];

  // redundant reduce: m = colsum(partial rows of batch b) / 4096
  {
    const float* pb = partial + (size_t)b * 64 * 256 + tid;
    float s0 = 0.f, s1 = 0.f, s2 = 0.f, s3 = 0.f;
    for (int p = 0; p < 64; p += 4) {
      s0 += pb[(size_t)(p + 0) * 256];
      s1 += pb[(size_t)(p + 1) * 256];
      s2 += pb[(size_t)(p + 2) * 256];
      s3 += pb[(size_t)(p + 3) * 256];
    }
    m[tid] = (s0 + s1 + s2 + s3) * (1.0f / 4096.0f);
  }
  __syncthreads();

  // 32-col slice of m @ Wkl (32 cols x 8 K-splits)
  {
    int c = tid & 31, ks = tid >> 5;
    const float* wcol = Wkl + cg * 32 + c;
    float a0 = 0.f, a1 = 0.f, a2 = 0.f, a3 = 0.f;
    int p0 = ks * 32;
    for (int p = p0; p < p0 + 32; p += 4) {
      a0 += m[p + 0] * wcol[(size_t)(p + 0) * 256];
      a1 += m[p + 1] * wcol[(size_t)(p + 1) * 256];
      a2 += m[p + 2] * wcol[(size_t)(p + 2) * 256];
      a3 += m[p + 3] * wcol[(size_t)(p + 3) * 256];
    }
    red[tid] = a0 + a1 + a2 + a3;
  }
  __syncthreads();
  if (tid < 32) {
    float v = bkl[cg * 32 + tid];
#pragma unroll
    for (int g = 0; g < 8; ++g) v += red[g * 32 + tid];
    oc[tid] = v > 0.f ? v : 0.f;
  }
  __syncthreads();

  // write 128 rows x 32 cols
  {
    int f4c = tid & 7, r0 = tid >> 3;
    float4 c4 = {oc[f4c * 4], oc[f4c * 4 + 1], oc[f4c * 4 + 2], oc[f4c * 4 + 3]};
    size_t base = ((size_t)b * 4096 + (size_t)rg * 128) * 256 + cg * 32;
#pragma unroll
    for (int pass = 0; pass < 4; ++pass) {
      int row = pass * 32 + r0;
      *(float4*)(out + base + (size_t)row * 256 + f4c * 4) = c4;
    }
  }
}

extern "C" void kernel_launch(void* const* d_in, const int* in_sizes, int n_in,
                              void* d_out, int out_size, void* d_ws, size_t ws_size,
                              hipStream_t stream) {
  const float* x  = (const float*)d_in[0];
  const float* Wk = (const float*)d_in[3];
  const float* bk = (const float*)d_in[4];
  const float* Wl = (const float*)d_in[7];
  const float* bl = (const float*)d_in[8];

  char* ws = (char*)d_ws;
  float* partial = (float*)ws;               // 256 KB
  float* Wkl     = (float*)(ws + 262144);    // 256 KB
  float* bkl     = (float*)(ws + 524288);    // 1 KB
  float* out     = (float*)d_out;

  k_stage1<<<dim3(CSB + WKB + BKB), dim3(256), 0, stream>>>(x, Wk, bk, Wl, bl,
                                                            partial, Wkl, bkl);
  k_stage2<<<dim3(1024), dim3(256), 0, stream>>>(partial, Wkl, bkl, out);
}

// Round 10
// 19.789 us; speedup vs baseline: 11.9160x; 1.0348x over previous
//
#include <hip/hip_runtime.h>

typedef __attribute__((ext_vector_type(4))) float f32x4;

// out[b,t,:] = relu(mean_t(x_b) @ Wkl + bkl),  Wkl = Wk@Wl,  bkl = bk@Wl + bl
// (double-softmax attention is uniform to O(1e-8); validated r3-r5.)
//
// Two dispatches, ZERO device-scope sync (r6/r7/r8 measured: any in-kernel
// cross-block sync >= 45us over a kernel boundary on gfx950's 8-XCD fabric).
// Stage 2 trades a tiny redundant reduce (64KB/block from L2) for all syncs.

#define CSB 256      // colsum blocks (64 rows each)
#define WKB 1024     // Wkl tile blocks (8x8 tile each)
#define BKB 32       // bkl blocks (8 cols each)

__global__ __launch_bounds__(256) void k_stage1(const float* __restrict__ x,
    const float* __restrict__ Wk, const float* __restrict__ bk,
    const float* __restrict__ Wl, const float* __restrict__ bl,
    float* __restrict__ partial, float* __restrict__ Wkl,
    float* __restrict__ bkl) {
  int bid = blockIdx.x, tid = threadIdx.x;
  __shared__ float4 lred[3][64];
  __shared__ float red[256];

  if (bid < CSB) {
    // ---- column-sum of 64 rows of x -> partial[bid][0..255]
    const float4* xr = (const float4*)(x + (size_t)bid * 64 * 256);
    int d4 = tid & 63, rs = tid >> 6;
    float4 acc = {0.f, 0.f, 0.f, 0.f};
#pragma unroll
    for (int i = 0; i < 16; ++i) {
      float4 v = xr[(size_t)(rs * 16 + i) * 64 + d4];
      acc.x += v.x; acc.y += v.y; acc.z += v.z; acc.w += v.w;
    }
    if (rs) lred[rs - 1][d4] = acc;
    __syncthreads();
    if (rs == 0) {
      float4 a1 = lred[0][d4], a2 = lred[1][d4], a3 = lred[2][d4];
      acc.x += a1.x + a2.x + a3.x;
      acc.y += a1.y + a2.y + a3.y;
      acc.z += a1.z + a2.z + a3.z;
      acc.w += a1.w + a2.w + a3.w;
      ((float4*)(partial + (size_t)bid * 256))[d4] = acc;
    }
  } else if (bid < CSB + WKB) {
    // ---- Wkl = Wk@Wl, one 8x8 tile per block (64 outputs x 4 K-splits)
    int t = bid - CSB;
    int i0 = (t >> 5) * 8, j0 = (t & 31) * 8;
    int oi = tid & 63, ks = tid >> 6;
    int i = i0 + (oi >> 3), j = j0 + (oi & 7);
    const float* wkr = Wk + i * 256 + ks * 64;
    const float* wlc = Wl + (ks * 64) * 256 + j;
    float s0 = 0.f, s1 = 0.f, s2 = 0.f, s3 = 0.f;
    for (int k = 0; k < 64; k += 4) {
      s0 += wkr[k + 0] * wlc[(k + 0) * 256];
      s1 += wkr[k + 1] * wlc[(k + 1) * 256];
      s2 += wkr[k + 2] * wlc[(k + 2) * 256];
      s3 += wkr[k + 3] * wlc[(k + 3) * 256];
    }
    red[tid] = s0 + s1 + s2 + s3;
    __syncthreads();
    if (tid < 64) {
      int ii = i0 + (tid >> 3), jj = j0 + (tid & 7);
      Wkl[ii * 256 + jj] = red[tid] + red[tid + 64] + red[tid + 128] + red[tid + 192];
    }
  } else {
    // ---- bkl = bk@Wl + bl, 8 cols per block (8 cols x 32 K-splits)
    int t = bid - CSB - WKB;
    int c = tid & 7, ks = tid >> 3;
    int j = t * 8 + c;
    float s = 0.f;
#pragma unroll
    for (int i2 = ks * 8; i2 < ks * 8 + 8; ++i2) s += bk[i2] * Wl[i2 * 256 + j];
    red[tid] = s;
    __syncthreads();
    if (tid < 8) {
      float v = 0.f;
#pragma unroll
      for (int g = 0; g < 32; ++g) v += red[g * 8 + tid];
      bkl[t * 8 + tid] = v + bl[t * 8 + tid];
    }
  }
}

__global__ __launch_bounds__(256) void k_stage2(const float* __restrict__ partial,
    const float* __restrict__ Wkl, const float* __restrict__ bkl,
    float* __restrict__ out) {
  // bid -> (b, cg, rg): batch, 32-col group (8), 128-row group (32)
  int bid = blockIdx.x, tid = threadIdx.x;
  int b = bid >> 8, cg = (bid >> 5) & 7, rg = bid & 31;
  __shared__ float4 lred[3][64];
  __shared__ float m[256];
  __shared__ float red[256];
  __shared__ float oc[32];

  // redundant reduce (float4, stage1 pattern): m = colsum(partial_b) / 4096
  {
    const float4* pb = (const float4*)(partial + (size_t)b * 64 * 256);
    int d4 = tid & 63, rs = tid >> 6;
    float4 acc = {0.f, 0.f, 0.f, 0.f};
#pragma unroll
    for (int i = 0; i < 16; ++i) {
      float4 v = pb[(size_t)(rs * 16 + i) * 64 + d4];
      acc.x += v.x; acc.y += v.y; acc.z += v.z; acc.w += v.w;
    }
    if (rs) lred[rs - 1][d4] = acc;
    __syncthreads();
    if (rs == 0) {
      float4 a1 = lred[0][d4], a2 = lred[1][d4], a3 = lred[2][d4];
      const float inv = 1.0f / 4096.0f;
      m[d4 * 4 + 0] = (acc.x + a1.x + a2.x + a3.x) * inv;
      m[d4 * 4 + 1] = (acc.y + a1.y + a2.y + a3.y) * inv;
      m[d4 * 4 + 2] = (acc.z + a1.z + a2.z + a3.z) * inv;
      m[d4 * 4 + 3] = (acc.w + a1.w + a2.w + a3.w) * inv;
    }
  }
  __syncthreads();

  // 32-col slice of m @ Wkl (32 cols x 8 K-splits)
  {
    int c = tid & 31, ks = tid >> 5;
    const float* wcol = Wkl + cg * 32 + c;
    float a0 = 0.f, a1 = 0.f, a2 = 0.f, a3 = 0.f;
    int p0 = ks * 32;
    for (int p = p0; p < p0 + 32; p += 4) {
      a0 += m[p + 0] * wcol[(size_t)(p + 0) * 256];
      a1 += m[p + 1] * wcol[(size_t)(p + 1) * 256];
      a2 += m[p + 2] * wcol[(size_t)(p + 2) * 256];
      a3 += m[p + 3] * wcol[(size_t)(p + 3) * 256];
    }
    red[tid] = a0 + a1 + a2 + a3;
  }
  __syncthreads();
  if (tid < 32) {
    float v = bkl[cg * 32 + tid];
#pragma unroll
    for (int g = 0; g < 8; ++g) v += red[g * 32 + tid];
    oc[tid] = v > 0.f ? v : 0.f;
  }
  __syncthreads();

  // write 128 rows x 32 cols (nontemporal: never re-read, keep out of L2)
  {
    int f4c = tid & 7, r0 = tid >> 3;
    f32x4 c4 = {oc[f4c * 4], oc[f4c * 4 + 1], oc[f4c * 4 + 2], oc[f4c * 4 + 3]};
    size_t base = ((size_t)b * 4096 + (size_t)rg * 128) * 256 + cg * 32;
#pragma unroll
    for (int pass = 0; pass < 4; ++pass) {
      int row = pass * 32 + r0;
      __builtin_nontemporal_store(c4, (f32x4*)(out + base + (size_t)row * 256 + f4c * 4));
    }
  }
}

extern "C" void kernel_launch(void* const* d_in, const int* in_sizes, int n_in,
                              void* d_out, int out_size, void* d_ws, size_t ws_size,
                              hipStream_t stream) {
  const float* x  = (const float*)d_in[0];
  const float* Wk = (const float*)d_in[3];
  const float* bk = (const float*)d_in[4];
  const float* Wl = (const float*)d_in[7];
  const float* bl = (const float*)d_in[8];

  char* ws = (char*)d_ws;
  float* partial = (float*)ws;               // 256 KB
  float* Wkl     = (float*)(ws + 262144);    // 256 KB
  float* bkl     = (float*)(ws + 524288);    // 1 KB
  float* out     = (float*)d_out;

  k_stage1<<<dim3(CSB + WKB + BKB), dim3(256), 0, stream>>>(x, Wk, bk, Wl, bl,
                                                            partial, Wkl, bkl);
  k_stage2<<<dim3(1024), dim3(256), 0, stream>>>(partial, Wkl, bkl, out);
}

// Round 11
// 18.607 us; speedup vs baseline: 12.6727x; 1.0635x over previous
//
#include <hip/hip_runtime.h>

typedef __attribute__((ext_vector_type(4))) float f32x4;

// out[b,t,:] = relu(mean_t(x_b) @ Wkl + bkl),  Wkl = Wk@Wl,  bkl = bk@Wl + bl
// (double-softmax attention is uniform to O(1e-8); validated r3-r5.)
//
// Two dispatches, ZERO device-scope sync (r6/r7/r8 measured: any in-kernel
// cross-block sync >= 45us over a kernel boundary on gfx950's 8-XCD fabric).
// Stage 2 trades a small redundant reduce (32KB/block from L2) for all syncs.

#define CSB 128      // colsum blocks (128 rows each)
#define WKB 1024     // Wkl tile blocks (8x8 tile each)
#define BKB 32       // bkl blocks (8 cols each)

__global__ __launch_bounds__(256) void k_stage1(const float* __restrict__ x,
    const float* __restrict__ Wk, const float* __restrict__ bk,
    const float* __restrict__ Wl, const float* __restrict__ bl,
    float* __restrict__ partial, float* __restrict__ Wkl,
    float* __restrict__ bkl) {
  int bid = blockIdx.x, tid = threadIdx.x;
  __shared__ f32x4 lred[3][64];
  __shared__ float red[256];

  if (bid < CSB) {
    // ---- column-sum of 128 rows of x -> partial[bid][0..255]
    // x is read exactly once per call: nontemporal (no L2 retention).
    const f32x4* xr = (const f32x4*)(x + (size_t)bid * 128 * 256);
    int d4 = tid & 63, rs = tid >> 6;
    f32x4 acc = {0.f, 0.f, 0.f, 0.f};
#pragma unroll
    for (int i = 0; i < 32; ++i) {
      f32x4 v = __builtin_nontemporal_load(xr + (size_t)(rs * 32 + i) * 64 + d4);
      acc += v;
    }
    if (rs) lred[rs - 1][d4] = acc;
    __syncthreads();
    if (rs == 0) {
      acc += lred[0][d4] + lred[1][d4] + lred[2][d4];
      *((f32x4*)(partial + (size_t)bid * 256) + d4) = acc;
    }
  } else if (bid < CSB + WKB) {
    // ---- Wkl = Wk@Wl, one 8x8 tile per block (64 outputs x 4 K-splits)
    int t = bid - CSB;
    int i0 = (t >> 5) * 8, j0 = (t & 31) * 8;
    int oi = tid & 63, ks = tid >> 6;
    int i = i0 + (oi >> 3), j = j0 + (oi & 7);
    const float* wkr = Wk + i * 256 + ks * 64;
    const float* wlc = Wl + (ks * 64) * 256 + j;
    float s0 = 0.f, s1 = 0.f, s2 = 0.f, s3 = 0.f;
    for (int k = 0; k < 64; k += 4) {
      s0 += wkr[k + 0] * wlc[(k + 0) * 256];
      s1 += wkr[k + 1] * wlc[(k + 1) * 256];
      s2 += wkr[k + 2] * wlc[(k + 2) * 256];
      s3 += wkr[k + 3] * wlc[(k + 3) * 256];
    }
    red[tid] = s0 + s1 + s2 + s3;
    __syncthreads();
    if (tid < 64) {
      int ii = i0 + (tid >> 3), jj = j0 + (tid & 7);
      Wkl[ii * 256 + jj] = red[tid] + red[tid + 64] + red[tid + 128] + red[tid + 192];
    }
  } else {
    // ---- bkl = bk@Wl + bl, 8 cols per block (8 cols x 32 K-splits)
    int t = bid - CSB - WKB;
    int c = tid & 7, ks = tid >> 3;
    int j = t * 8 + c;
    float s = 0.f;
#pragma unroll
    for (int i2 = ks * 8; i2 < ks * 8 + 8; ++i2) s += bk[i2] * Wl[i2 * 256 + j];
    red[tid] = s;
    __syncthreads();
    if (tid < 8) {
      float v = 0.f;
#pragma unroll
      for (int g = 0; g < 32; ++g) v += red[g * 8 + tid];
      bkl[t * 8 + tid] = v + bl[t * 8 + tid];
    }
  }
}

__global__ __launch_bounds__(256) void k_stage2(const float* __restrict__ partial,
    const float* __restrict__ Wkl, const float* __restrict__ bkl,
    float* __restrict__ out) {
  // bid -> (b, cg, rg): batch, 32-col group (8), 128-row group (32)
  int bid = blockIdx.x, tid = threadIdx.x;
  int b = bid >> 8, cg = (bid >> 5) & 7, rg = bid & 31;
  __shared__ f32x4 lred[3][64];
  __shared__ float m[256];
  __shared__ float red[256];
  __shared__ float oc[32];

  // redundant reduce: m = colsum(partial_b[32 rows]) / 4096  (32KB from L2)
  {
    const f32x4* pb = (const f32x4*)(partial + (size_t)b * 32 * 256);
    int d4 = tid & 63, rs = tid >> 6;
    f32x4 acc = {0.f, 0.f, 0.f, 0.f};
#pragma unroll
    for (int i = 0; i < 8; ++i) acc += pb[(size_t)(rs * 8 + i) * 64 + d4];
    if (rs) lred[rs - 1][d4] = acc;
    __syncthreads();
    if (rs == 0) {
      acc += lred[0][d4] + lred[1][d4] + lred[2][d4];
      const float inv = 1.0f / 4096.0f;
      m[d4 * 4 + 0] = acc.x * inv;
      m[d4 * 4 + 1] = acc.y * inv;
      m[d4 * 4 + 2] = acc.z * inv;
      m[d4 * 4 + 3] = acc.w * inv;
    }
  }
  __syncthreads();

  // 32-col slice of m @ Wkl (32 cols x 8 K-splits)
  {
    int c = tid & 31, ks = tid >> 5;
    const float* wcol = Wkl + cg * 32 + c;
    float a0 = 0.f, a1 = 0.f, a2 = 0.f, a3 = 0.f;
    int p0 = ks * 32;
    for (int p = p0; p < p0 + 32; p += 4) {
      a0 += m[p + 0] * wcol[(size_t)(p + 0) * 256];
      a1 += m[p + 1] * wcol[(size_t)(p + 1) * 256];
      a2 += m[p + 2] * wcol[(size_t)(p + 2) * 256];
      a3 += m[p + 3] * wcol[(size_t)(p + 3) * 256];
    }
    red[tid] = a0 + a1 + a2 + a3;
  }
  __syncthreads();
  if (tid < 32) {
    float v = bkl[cg * 32 + tid];
#pragma unroll
    for (int g = 0; g < 8; ++g) v += red[g * 32 + tid];
    oc[tid] = v > 0.f ? v : 0.f;
  }
  __syncthreads();

  // write 128 rows x 32 cols (nontemporal: never re-read, keep out of L2)
  {
    int f4c = tid & 7, r0 = tid >> 3;
    f32x4 c4 = {oc[f4c * 4], oc[f4c * 4 + 1], oc[f4c * 4 + 2], oc[f4c * 4 + 3]};
    size_t base = ((size_t)b * 4096 + (size_t)rg * 128) * 256 + cg * 32;
#pragma unroll
    for (int pass = 0; pass < 4; ++pass) {
      int row = pass * 32 + r0;
      __builtin_nontemporal_store(c4, (f32x4*)(out + base + (size_t)row * 256 + f4c * 4));
    }
  }
}

extern "C" void kernel_launch(void* const* d_in, const int* in_sizes, int n_in,
                              void* d_out, int out_size, void* d_ws, size_t ws_size,
                              hipStream_t stream) {
  const float* x  = (const float*)d_in[0];
  const float* Wk = (const float*)d_in[3];
  const float* bk = (const float*)d_in[4];
  const float* Wl = (const float*)d_in[7];
  const float* bl = (const float*)d_in[8];

  char* ws = (char*)d_ws;
  float* partial = (float*)ws;               // 128 KB
  float* Wkl     = (float*)(ws + 262144);    // 256 KB
  float* bkl     = (float*)(ws + 524288);    // 1 KB
  float* out     = (float*)d_out;

  k_stage1<<<dim3(CSB + WKB + BKB), dim3(256), 0, stream>>>(x, Wk, bk, Wl, bl,
                                                            partial, Wkl, bkl);
  k_stage2<<<dim3(1024), dim3(256), 0, stream>>>(partial, Wkl, bkl, out);
}

// Round 12
// 17.937 us; speedup vs baseline: 13.1460x; 1.0373x over previous
//
#include <hip/hip_runtime.h>

typedef __attribute__((ext_vector_type(4))) float f32x4;

// out[b,t,:] = relu(mean_t(x_b) @ Wkl + bkl),  Wkl = Wk@Wl,  bkl = bk@Wl + bl
// (double-softmax attention is uniform to O(1e-8); validated r3-r5.)
//
// Two dispatches, ZERO device-scope sync (r6/r7/r8 measured: any in-kernel
// cross-block sync >= 45us over a kernel boundary on gfx950's 8-XCD fabric).
// Stage 2 trades a small redundant reduce (64KB/block from L2) for all syncs.

#define CSB 256      // colsum blocks (64 rows each)
#define WKB 1024     // Wkl tile blocks (8x8 tile each)
#define BKB 32       // bkl blocks (8 cols each)

__global__ __launch_bounds__(256) void k_stage1(const float* __restrict__ x,
    const float* __restrict__ Wk, const float* __restrict__ bk,
    const float* __restrict__ Wl, const float* __restrict__ bl,
    float* __restrict__ partial, float* __restrict__ Wkl,
    float* __restrict__ bkl) {
  int bid = blockIdx.x, tid = threadIdx.x;
  __shared__ f32x4 lred[3][64];
  __shared__ float red[256];

  if (bid < CSB) {
    // ---- column-sum of 64 rows of x -> partial[bid][0..255]
    // x is read exactly once per call: nontemporal (no L2 retention).
    const f32x4* xr = (const f32x4*)(x + (size_t)bid * 64 * 256);
    int d4 = tid & 63, rs = tid >> 6;
    f32x4 acc = {0.f, 0.f, 0.f, 0.f};
#pragma unroll
    for (int i = 0; i < 16; ++i) {
      f32x4 v = __builtin_nontemporal_load(xr + (size_t)(rs * 16 + i) * 64 + d4);
      acc += v;
    }
    if (rs) lred[rs - 1][d4] = acc;
    __syncthreads();
    if (rs == 0) {
      acc += lred[0][d4] + lred[1][d4] + lred[2][d4];
      *((f32x4*)(partial + (size_t)bid * 256) + d4) = acc;
    }
  } else if (bid < CSB + WKB) {
    // ---- Wkl = Wk@Wl, one 8x8 tile per block (64 outputs x 4 K-splits)
    int t = bid - CSB;
    int i0 = (t >> 5) * 8, j0 = (t & 31) * 8;
    int oi = tid & 63, ks = tid >> 6;
    int i = i0 + (oi >> 3), j = j0 + (oi & 7);
    const float* wkr = Wk + i * 256 + ks * 64;
    const float* wlc = Wl + (ks * 64) * 256 + j;
    float s0 = 0.f, s1 = 0.f, s2 = 0.f, s3 = 0.f;
    for (int k = 0; k < 64; k += 4) {
      s0 += wkr[k + 0] * wlc[(k + 0) * 256];
      s1 += wkr[k + 1] * wlc[(k + 1) * 256];
      s2 += wkr[k + 2] * wlc[(k + 2) * 256];
      s3 += wkr[k + 3] * wlc[(k + 3) * 256];
    }
    red[tid] = s0 + s1 + s2 + s3;
    __syncthreads();
    if (tid < 64) {
      int ii = i0 + (tid >> 3), jj = j0 + (tid & 7);
      Wkl[ii * 256 + jj] = red[tid] + red[tid + 64] + red[tid + 128] + red[tid + 192];
    }
  } else {
    // ---- bkl = bk@Wl + bl, 8 cols per block (8 cols x 32 K-splits)
    int t = bid - CSB - WKB;
    int c = tid & 7, ks = tid >> 3;
    int j = t * 8 + c;
    float s = 0.f;
#pragma unroll
    for (int i2 = ks * 8; i2 < ks * 8 + 8; ++i2) s += bk[i2] * Wl[i2 * 256 + j];
    red[tid] = s;
    __syncthreads();
    if (tid < 8) {
      float v = 0.f;
#pragma unroll
      for (int g = 0; g < 32; ++g) v += red[g * 8 + tid];
      bkl[t * 8 + tid] = v + bl[t * 8 + tid];
    }
  }
}

__global__ __launch_bounds__(256) void k_stage2(const float* __restrict__ partial,
    const float* __restrict__ Wkl, const float* __restrict__ bkl,
    float* __restrict__ out) {
  // 512 blocks: bid -> (b, cg, rg): batch, 32-col group (8), 256-row group (16)
  int bid = blockIdx.x, tid = threadIdx.x;
  int b = bid >> 7, cg = (bid >> 4) & 7, rg = bid & 15;
  __shared__ f32x4 lred[3][64];
  __shared__ float m[256];
  __shared__ float red[256];
  __shared__ float oc[32];

  // redundant reduce: m = colsum(partial_b[64 rows]) / 4096  (64KB from L2)
  {
    const f32x4* pb = (const f32x4*)(partial + (size_t)b * 64 * 256);
    int d4 = tid & 63, rs = tid >> 6;
    f32x4 acc = {0.f, 0.f, 0.f, 0.f};
#pragma unroll
    for (int i = 0; i < 16; ++i) acc += pb[(size_t)(rs * 16 + i) * 64 + d4];
    if (rs) lred[rs - 1][d4] = acc;
    __syncthreads();
    if (rs == 0) {
      acc += lred[0][d4] + lred[1][d4] + lred[2][d4];
      const float inv = 1.0f / 4096.0f;
      m[d4 * 4 + 0] = acc.x * inv;
      m[d4 * 4 + 1] = acc.y * inv;
      m[d4 * 4 + 2] = acc.z * inv;
      m[d4 * 4 + 3] = acc.w * inv;
    }
  }
  __syncthreads();

  // 32-col slice of m @ Wkl (32 cols x 8 K-splits)
  {
    int c = tid & 31, ks = tid >> 5;
    const float* wcol = Wkl + cg * 32 + c;
    float a0 = 0.f, a1 = 0.f, a2 = 0.f, a3 = 0.f;
    int p0 = ks * 32;
    for (int p = p0; p < p0 + 32; p += 4) {
      a0 += m[p + 0] * wcol[(size_t)(p + 0) * 256];
      a1 += m[p + 1] * wcol[(size_t)(p + 1) * 256];
      a2 += m[p + 2] * wcol[(size_t)(p + 2) * 256];
      a3 += m[p + 3] * wcol[(size_t)(p + 3) * 256];
    }
    red[tid] = a0 + a1 + a2 + a3;
  }
  __syncthreads();
  if (tid < 32) {
    float v = bkl[cg * 32 + tid];
#pragma unroll
    for (int g = 0; g < 8; ++g) v += red[g * 32 + tid];
    oc[tid] = v > 0.f ? v : 0.f;
  }
  __syncthreads();

  // write 256 rows x 32 cols (nontemporal: never re-read, keep out of L2)
  {
    int f4c = tid & 7, r0 = tid >> 3;
    f32x4 c4 = {oc[f4c * 4], oc[f4c * 4 + 1], oc[f4c * 4 + 2], oc[f4c * 4 + 3]};
    size_t base = ((size_t)b * 4096 + (size_t)rg * 256) * 256 + cg * 32;
#pragma unroll
    for (int pass = 0; pass < 8; ++pass) {
      int row = pass * 32 + r0;
      __builtin_nontemporal_store(c4, (f32x4*)(out + base + (size_t)row * 256 + f4c * 4));
    }
  }
}

extern "C" void kernel_launch(void* const* d_in, const int* in_sizes, int n_in,
                              void* d_out, int out_size, void* d_ws, size_t ws_size,
                              hipStream_t stream) {
  const float* x  = (const float*)d_in[0];
  const float* Wk = (const float*)d_in[3];
  const float* bk = (const float*)d_in[4];
  const float* Wl = (const float*)d_in[7];
  const float* bl = (const float*)d_in[8];

  char* ws = (char*)d_ws;
  float* partial = (float*)ws;               // 256 KB
  float* Wkl     = (float*)(ws + 262144);    // 256 KB
  float* bkl     = (float*)(ws + 524288);    // 1 KB
  float* out     = (float*)d_out;

  k_stage1<<<dim3(CSB + WKB + BKB), dim3(256), 0, stream>>>(x, Wk, bk, Wl, bl,
                                                            partial, Wkl, bkl);
  k_stage2<<<dim3(512), dim3(256), 0, stream>>>(partial, Wkl, bkl, out);
}